// Round 17
// baseline (41.104 us; speedup 1.0000x reference)
//
#include <hip/hip_runtime.h>
#include <hip/hip_bf16.h>

#define CIN 32
#define HW 64
#define KK 64
#define NLEAF 8
#define PADDING 2
#define TH 4                    // tile rows
#define TCW 16                  // tile cols
#define WR 8                    // window rows = TH + 4
#define WC 20                   // window cols = TCW + 4
#define WPOS (CIN * WR * WC)    // 5120 positions; f32x4 each -> 81920 B LDS

typedef float f32x2 __attribute__((ext_vector_type(2)));
typedef float f32x4 __attribute__((ext_vector_type(4)));

__device__ __constant__ float d_C[16][4] = {
    {0, 0, 0, 0},  {0, 0, 0, 1},  {0, 1, 0, -1}, {0, 1, 0, 0},
    {0, 0, 1, -1}, {0, 0, 1, 0},  {0, 1, 1, -2}, {0, 1, 1, -1},
    {1, -1, -1, 1},{1, -1, -1, 2},{1, 0, -1, 0}, {1, 0, -1, 1},
    {1, -1, 0, 0}, {1, -1, 0, 1}, {1, 0, 0, -1}, {1, 0, 0, 0}
};

// Packed per-k uniform blob: blob[k*80 + 0..15]  = leaf BYTE offsets in the
// f32x4 window; blob[k*80 + 16 + node*4 + j] = coef. 64k x 80 dwords = 20 KB.
// Fully parallel prep: 4 blocks x 256 threads.
__global__ __launch_bounds__(256) void prep_kernel(
    const int* __restrict__ idx_h, const int* __restrict__ idx_w, const int* __restrict__ idx_c,
    const float* __restrict__ w0, const float* __restrict__ w1,
    const float* __restrict__ w2, const float* __restrict__ w3,
    float* __restrict__ blob)
{
    int tid = blockIdx.x * 256 + threadIdx.x;   // 0..1023

    {
        int k = tid >> 4, n = tid & 15;
        int s = n >> 3, leaf = n & 7;
        int o = s * (KK * NLEAF) + k * NLEAF + leaf;
        ((int*)blob)[k * 80 + n] =
            (idx_c[o] * (WR * WC) + idx_h[o] * WC + idx_w[o]) * 16;
    }

    if (tid < KK * 15) {
        int k = tid / 15, node = tid % 15;
        const float* wp; int n;
        if (node < 8)       { wp = w0; n = node; }
        else if (node < 12) { wp = w1; n = node - 8; }
        else if (node < 14) { wp = w2; n = node - 12; }
        else                { wp = w3; n = 0; }
        const float4* lp = (const float4*)(wp + (size_t)(n * KK + k) * 16);
        float4 L0 = lp[0], L1 = lp[1], L2 = lp[2], L3 = lp[3];
        float l[16] = {L0.x, L0.y, L0.z, L0.w, L1.x, L1.y, L1.z, L1.w,
                       L2.x, L2.y, L2.z, L2.w, L3.x, L3.y, L3.z, L3.w};
        float m = l[0];
        #pragma unroll
        for (int g = 1; g < 16; ++g) m = fmaxf(m, l[g]);
        float p[16], s = 0.f;
        #pragma unroll
        for (int g = 0; g < 16; ++g) { p[g] = __expf(l[g] - m); s += p[g]; }
        float inv = 1.f / s;
        float c0 = 0, c1 = 0, c2 = 0, c3 = 0;
        #pragma unroll
        for (int g = 0; g < 16; ++g) {
            float w = p[g] * inv;
            c0 = fmaf(w, d_C[g][0], c0);
            c1 = fmaf(w, d_C[g][1], c1);
            c2 = fmaf(w, d_C[g][2], c2);
            c3 = fmaf(w, d_C[g][3], c3);
        }
        float* o = blob + (k * 80 + 16 + node * 4);
        o[0] = c0; o[1] = c1; o[2] = c2; o[3] = c3;
    }
}

__device__ __forceinline__ f32x2 bc(float s) { return (f32x2){s, s}; }
__device__ __forceinline__ f32x2 gate2s(float c0, float c1, float c2, float c3,
                                        f32x2 a, f32x2 b) {
    return __builtin_elementwise_fma(b,
               __builtin_elementwise_fma(a, bc(c3), bc(c2)),
               __builtin_elementwise_fma(a, bc(c1), bc(c0)));
}

// blockIdx = tile*8 + grp; grp = kh*4 + quad -> XCD slot. 512 threads = 8
// waves; wave w covers k in [kh*32 + 4w, +4). lane = pixel of the 4x16 tile;
// f32x4 = 4 batch images -> every gather is one ds_read_b128.
// The wave's 4 k's uniforms (4 x 80 dwords) live lane-strided in 5 VGPRs;
// the k-loop extracts them via compile-time v_readlane -> ZERO uniform
// memory ops inside the loop (no SMEM/lgkmcnt mixing with the DS queue).
__global__ __launch_bounds__(512, 4) void logic_conv_kernel(
    const float* __restrict__ x, const float* __restrict__ blob,
    float* __restrict__ out)
{
    extern __shared__ f32x4 xt[];   // WPOS = 81920 B

    int tid  = threadIdx.x;
    int grp  = blockIdx.x & 7;
    int quad = grp & 3;
    int kh   = grp >> 2;
    int t    = blockIdx.x >> 3;        // tile 0..63
    int r0   = (t >> 2) * TH;
    int c0   = (t & 3) * TCW;

    int lane = tid & 63, wave = tid >> 6;
    int kbase = __builtin_amdgcn_readfirstlane(kh * 32 + wave * 4);

    // ---- wave-uniform blob -> 5 lane-strided VGPRs (issued early) ----
    unsigned cc[5];
    {
        const unsigned* bu = (const unsigned*)blob + kbase * 80 + lane;
        #pragma unroll
        for (int i = 0; i < 5; ++i) cc[i] = bu[i * 64];
    }

    const float* xb0 = x + (size_t)(4 * quad) * (CIN * HW * HW);
    const float* xb1 = xb0 + (CIN * HW * HW);
    const float* xb2 = xb1 + (CIN * HW * HW);
    const float* xb3 = xb2 + (CIN * HW * HW);

    // Stage packed padded 32x8x20 windows for 4 images (10 positions/thread).
    #pragma unroll
    for (int i = 0; i < 10; ++i) {
        int e  = tid + i * 512;
        int c  = e / (WR * WC);
        int r  = e - c * (WR * WC);
        int rr = r / WC;
        int cc2 = r - rr * WC;
        int ih = r0 + rr - PADDING, iw = c0 + cc2 - PADDING;
        f32x4 v = {0.f, 0.f, 0.f, 0.f};
        if ((unsigned)ih < HW && (unsigned)iw < HW) {
            int go = (c * HW + ih) * HW + iw;
            v.x = xb0[go];
            v.y = xb1[go];
            v.z = xb2[go];
            v.w = xb3[go];
        }
        xt[e] = v;
    }
    __syncthreads();

    int tr = lane >> 4, tc = lane & 15;
    int pxb   = (tr * WC + tc) * 16;           // byte offset in window
    int pxout = (r0 + tr) * HW + (c0 + tc);    // output element offset
    float* outB0 = out + ((size_t)(4 * quad) << 18);
    float* outB1 = outB0 + (1 << 18);
    float* outB2 = outB1 + (1 << 18);
    float* outB3 = outB2 + (1 << 18);
    const char* xtb = (const char*)xt;

#define RL(i)  __builtin_amdgcn_readlane(cc[(D + (i)) >> 6], (D + (i)) & 63)
#define RLF(i) __uint_as_float(RL(i))

    #pragma unroll 2
    for (int j = 0; j < 4; ++j) {
        const int D = j * 80;

        f32x2 gA[16], gB[16];
        #pragma unroll
        for (int n = 0; n < 16; ++n) {
            int off = (int)RL(n);
            f32x4 gv = *(const f32x4*)(xtb + (off + pxb));
            gA[n] = (f32x2){gv.x, gv.y};
            gB[n] = (f32x2){gv.z, gv.w};
        }

        f32x2 vA[8], vB[8];
        #pragma unroll
        for (int n = 0; n < 8; ++n) {
            float c0v = RLF(16 + 4 * n), c1v = RLF(17 + 4 * n);
            float c2v = RLF(18 + 4 * n), c3v = RLF(19 + 4 * n);
            vA[n] = gate2s(c0v, c1v, c2v, c3v, gA[n], gA[8 + n]);
            vB[n] = gate2s(c0v, c1v, c2v, c3v, gB[n], gB[8 + n]);
        }
        f32x2 uA[4], uB[4];
        #pragma unroll
        for (int n = 0; n < 4; ++n) {
            float c0v = RLF(48 + 4 * n), c1v = RLF(49 + 4 * n);
            float c2v = RLF(50 + 4 * n), c3v = RLF(51 + 4 * n);
            uA[n] = gate2s(c0v, c1v, c2v, c3v, vA[2 * n], vA[2 * n + 1]);
            uB[n] = gate2s(c0v, c1v, c2v, c3v, vB[2 * n], vB[2 * n + 1]);
        }
        float e0 = RLF(64), e1 = RLF(65), e2 = RLF(66), e3 = RLF(67);
        f32x2 sA0 = gate2s(e0, e1, e2, e3, uA[0], uA[1]);
        f32x2 sB0 = gate2s(e0, e1, e2, e3, uB[0], uB[1]);
        float f0 = RLF(68), f1 = RLF(69), f2 = RLF(70), f3 = RLF(71);
        f32x2 sA1 = gate2s(f0, f1, f2, f3, uA[2], uA[3]);
        f32x2 sB1 = gate2s(f0, f1, f2, f3, uB[2], uB[3]);
        float h0 = RLF(72), h1 = RLF(73), h2 = RLF(74), h3 = RLF(75);
        f32x2 qA = gate2s(h0, h1, h2, h3, sA0, sA1);
        f32x2 qB = gate2s(h0, h1, h2, h3, sB0, sB1);

        int ko = ((kbase + j) << 12) + pxout;
        __builtin_nontemporal_store(qA.x, &outB0[ko]);
        __builtin_nontemporal_store(qA.y, &outB1[ko]);
        __builtin_nontemporal_store(qB.x, &outB2[ko]);
        __builtin_nontemporal_store(qB.y, &outB3[ko]);
    }
#undef RL
#undef RLF
}

extern "C" void kernel_launch(void* const* d_in, const int* in_sizes, int n_in,
                              void* d_out, int out_size, void* d_ws, size_t ws_size,
                              hipStream_t stream) {
    const float* x     = (const float*)d_in[0];
    const int*   idx_h = (const int*)d_in[1];
    const int*   idx_w = (const int*)d_in[2];
    const int*   idx_c = (const int*)d_in[3];
    const float* w0    = (const float*)d_in[4];
    const float* w1    = (const float*)d_in[5];
    const float* w2    = (const float*)d_in[6];
    const float* w3    = (const float*)d_in[7];
    float* out  = (float*)d_out;
    float* blob = (float*)d_ws;                       // 20,480 B

    hipLaunchKernelGGL(prep_kernel, dim3(4), dim3(256), 0, stream,
                       idx_h, idx_w, idx_c, w0, w1, w2, w3, blob);
    // 64 tiles * (4 quads x 2 kh) = 512 blocks, 512 threads, 80 KB dynamic LDS
    hipLaunchKernelGGL(logic_conv_kernel, dim3(512), dim3(512),
                       WPOS * sizeof(f32x4), stream,
                       x, blob, out);
}

// Round 18
// 24.244 us; speedup vs baseline: 1.6955x; 1.6955x over previous
//
#include <hip/hip_runtime.h>
#include <hip/hip_bf16.h>

#define CIN 32
#define HW 64
#define KK 64
#define NLEAF 8
#define PADDING 2
#define PW 68
#define PIMG (PW * PW)          // 4624
#define NPADBLK 2312            // 16*32*4624 / 1024, 4 elements per thread

typedef float f32x4 __attribute__((ext_vector_type(4)));

__device__ __constant__ float d_C[16][4] = {
    {0, 0, 0, 0},  {0, 0, 0, 1},  {0, 1, 0, -1}, {0, 1, 0, 0},
    {0, 0, 1, -1}, {0, 0, 1, 0},  {0, 1, 1, -2}, {0, 1, 1, -1},
    {1, -1, -1, 1},{1, -1, -1, 2},{1, 0, -1, 0}, {1, 0, -1, 1},
    {1, -1, 0, 0}, {1, -1, 0, 1}, {1, 0, 0, -1}, {1, 0, 0, 0}
};

// blocks [0,2312): zero-pad x -> xpad[b,c,68,68].
// blocks 2312..2315 (1024 threads): loffA[k*16+n] = c*4624 + dh*68 + dw
// (element offset; gather addr = loff + oh*68 + ow), plus coefA (softmax.C).
__global__ __launch_bounds__(256) void prep_kernel(
    const float* __restrict__ x,
    const int* __restrict__ idx_h, const int* __restrict__ idx_w, const int* __restrict__ idx_c,
    const float* __restrict__ w0, const float* __restrict__ w1,
    const float* __restrict__ w2, const float* __restrict__ w3,
    float* __restrict__ coefA, int* __restrict__ loffA, float* __restrict__ xpad)
{
    int blk = blockIdx.x;
    if (blk < NPADBLK) {
        int t = blk * 256 + threadIdx.x;
        #pragma unroll
        for (int it = 0; it < 4; ++it) {
            int e  = t + it * (NPADBLK * 256);
            int bc = e / PIMG;
            int r  = e - bc * PIMG;
            int ph = r / PW;
            int pw = r - ph * PW;
            int ih = ph - PADDING, iw = pw - PADDING;
            float v = 0.f;
            if ((unsigned)ih < HW && (unsigned)iw < HW)
                v = x[bc * (HW * HW) + ih * HW + iw];
            xpad[e] = v;
        }
        return;
    }
    int t = (blk - NPADBLK) * 256 + threadIdx.x;    // 0..1023

    {   // leaf offsets
        int k = t >> 4, n = t & 15;
        int s = n >> 3, leaf = n & 7;
        int o = s * (KK * NLEAF) + k * NLEAF + leaf;
        loffA[t] = idx_c[o] * PIMG + idx_h[o] * PW + idx_w[o];
    }

    if (t < KK * 15) {
        int k = t / 15, node = t % 15;
        const float* wp; int n;
        if (node < 8)       { wp = w0; n = node; }
        else if (node < 12) { wp = w1; n = node - 8; }
        else if (node < 14) { wp = w2; n = node - 12; }
        else                { wp = w3; n = 0; }
        const float4* lp = (const float4*)(wp + (size_t)(n * KK + k) * 16);
        float4 L0 = lp[0], L1 = lp[1], L2 = lp[2], L3 = lp[3];
        float l[16] = {L0.x, L0.y, L0.z, L0.w, L1.x, L1.y, L1.z, L1.w,
                       L2.x, L2.y, L2.z, L2.w, L3.x, L3.y, L3.z, L3.w};
        float m = l[0];
        #pragma unroll
        for (int g = 1; g < 16; ++g) m = fmaxf(m, l[g]);
        float p[16], s = 0.f;
        #pragma unroll
        for (int g = 0; g < 16; ++g) { p[g] = __expf(l[g] - m); s += p[g]; }
        float inv = 1.f / s;
        float c0 = 0, c1 = 0, c2 = 0, c3 = 0;
        #pragma unroll
        for (int g = 0; g < 16; ++g) {
            float w = p[g] * inv;
            c0 = fmaf(w, d_C[g][0], c0);
            c1 = fmaf(w, d_C[g][1], c1);
            c2 = fmaf(w, d_C[g][2], c2);
            c3 = fmaf(w, d_C[g][3], c3);
        }
        float* o = coefA + (k * 60 + node * 4);
        o[0] = c0; o[1] = c1; o[2] = c2; o[3] = c3;
    }
}

__device__ __forceinline__ f32x4 bc4(float s) { return (f32x4){s, s, s, s}; }
__device__ __forceinline__ f32x4 gate4(const float* c, f32x4 a, f32x4 b) {
    return __builtin_elementwise_fma(b,
               __builtin_elementwise_fma(a, bc4(c[3]), bc4(c[2])),
               __builtin_elementwise_fma(a, bc4(c[1]), bc4(c[0])));
}

// One block per (b,k): blk = k*16 + b  (b = blk&15 -> XCD = b%8: images b and
// b+8 share one XCD whose L2 holds their 1.2 MB of xpad -> gathers = L2 hits).
// 256 threads; each lane computes 4 consecutive pixels: per leaf ONE
// global_load_dwordx4 (contiguous in ow), gates as 4-wide packed FMA.
// No LDS, no barriers; gathers on vmcnt (uniform s_loads no longer drain them).
__global__ __launch_bounds__(256) void logic_conv_kernel(
    const float* __restrict__ xpad, const int* __restrict__ loffA,
    const float* __restrict__ coefA, float* __restrict__ out)
{
    int blk = blockIdx.x;
    int b = blk & 15, k = blk >> 4;

    const float* xpb = xpad + (size_t)b * (CIN * PIMG);

    // per-leaf SGPR base pointers
    const float* bp[16];
    #pragma unroll
    for (int n = 0; n < 16; ++n)
        bp[n] = xpb + __builtin_amdgcn_readfirstlane(loffA[(k << 4) + n]);

    // coefs as broadcast VGPRs (keeps SGPR budget for the 16 base pairs)
    float cf[15][4];
    #pragma unroll
    for (int nd = 0; nd < 15; ++nd) {
        f32x4 c4 = ((const f32x4*)(coefA + k * 60))[nd];
        cf[nd][0] = c4.x; cf[nd][1] = c4.y; cf[nd][2] = c4.z; cf[nd][3] = c4.w;
    }

    float* outp = out + ((size_t)(b * KK + k) << 12);
    int p0 = threadIdx.x << 2;

    #pragma unroll
    for (int it = 0; it < 4; ++it) {
        int p    = p0 + it * 1024;
        int voff = (p >> 6) * PW + (p & 63);    // oh*68 + ow

        f32x4 g[16];
        #pragma unroll
        for (int n = 0; n < 16; ++n)
            g[n] = *(const f32x4*)(bp[n] + voff);

        f32x4 v[8];
        #pragma unroll
        for (int n = 0; n < 8; ++n)
            v[n] = gate4(cf[n], g[n], g[8 + n]);
        f32x4 u[4];
        #pragma unroll
        for (int n = 0; n < 4; ++n)
            u[n] = gate4(cf[8 + n], v[2 * n], v[2 * n + 1]);
        f32x4 t0 = gate4(cf[12], u[0], u[1]);
        f32x4 t1 = gate4(cf[13], u[2], u[3]);
        f32x4 r  = gate4(cf[14], t0, t1);

        __builtin_nontemporal_store(r, (f32x4*)(outp + p));
    }
}

extern "C" void kernel_launch(void* const* d_in, const int* in_sizes, int n_in,
                              void* d_out, int out_size, void* d_ws, size_t ws_size,
                              hipStream_t stream) {
    const float* x     = (const float*)d_in[0];
    const int*   idx_h = (const int*)d_in[1];
    const int*   idx_w = (const int*)d_in[2];
    const int*   idx_c = (const int*)d_in[3];
    const float* w0    = (const float*)d_in[4];
    const float* w1    = (const float*)d_in[5];
    const float* w2    = (const float*)d_in[6];
    const float* w3    = (const float*)d_in[7];
    float* out = (float*)d_out;

    float* coefA = (float*)d_ws;                         // 15,360 B
    int*   loffA = (int*)((char*)d_ws + 16384);          // 4,096 B
    float* xpad  = (float*)((char*)d_ws + 32768);        // 9,469,952 B

    hipLaunchKernelGGL(prep_kernel, dim3(NPADBLK + 4), dim3(256), 0, stream,
                       x, idx_h, idx_w, idx_c, w0, w1, w2, w3, coefA, loffA, xpad);
    // 64 k * 16 b = 1024 blocks, 256 threads
    hipLaunchKernelGGL(logic_conv_kernel, dim3(1024), dim3(256), 0, stream,
                       xpad, loffA, coefA, out);
}